// Round 1
// baseline (848.464 us; speedup 1.0000x reference)
//
#include <hip/hip_runtime.h>

typedef unsigned short u16;
typedef short s16x8 __attribute__((ext_vector_type(8)));
typedef float f32x4 __attribute__((ext_vector_type(4)));

#define D_MODEL 1024
#define NH 16
#define DH 64
#define SEQ 2048
#define NBATCH 2
#define MROWS (NBATCH * SEQ) /* 4096 */

__device__ __forceinline__ u16 f2bf(float f) {
  unsigned u = __builtin_bit_cast(unsigned, f);
  u += 0x7fffu + ((u >> 16) & 1u); // RNE
  return (u16)(u >> 16);
}

__device__ __forceinline__ f32x4 mfma16(s16x8 a, s16x8 b, f32x4 c) {
  return __builtin_amdgcn_mfma_f32_16x16x32_bf16(a, b, c, 0, 0, 0);
}

__device__ __forceinline__ s16x8 lds8(const u16* p) { return *(const s16x8*)p; }

__device__ __forceinline__ float qmax16(float x) {
  x = fmaxf(x, __shfl_xor(x, 1));
  x = fmaxf(x, __shfl_xor(x, 2));
  x = fmaxf(x, __shfl_xor(x, 4));
  x = fmaxf(x, __shfl_xor(x, 8));
  return x;
}
__device__ __forceinline__ float qsum16(float x) {
  x += __shfl_xor(x, 1);
  x += __shfl_xor(x, 2);
  x += __shfl_xor(x, 4);
  x += __shfl_xor(x, 8);
  return x;
}

// ---------------- conversion kernels ----------------

__global__ __launch_bounds__(256) void convert_x(const float* __restrict__ q, const float* __restrict__ k,
                                                 const float* __restrict__ v, u16* __restrict__ xq,
                                                 u16* __restrict__ xk, u16* __restrict__ xv) {
  const int z = blockIdx.z;
  const float* src = z == 0 ? q : (z == 1 ? k : v);
  u16* dst = z == 0 ? xq : (z == 1 ? xk : xv);
  const size_t i = ((size_t)blockIdx.x * 256 + threadIdx.x) * 4;
  float4 f = *(const float4*)&src[i];
  ushort4 o;
  o.x = f2bf(f.x); o.y = f2bf(f.y); o.z = f2bf(f.z); o.w = f2bf(f.w);
  *(ushort4*)&dst[i] = o;
}

// W [K][N] fp32 -> Wt [N][K] bf16
__global__ __launch_bounds__(256) void transw(const float* __restrict__ w0, const float* __restrict__ w1,
                                              const float* __restrict__ w2, const float* __restrict__ w3,
                                              u16* __restrict__ t0, u16* __restrict__ t1, u16* __restrict__ t2,
                                              u16* __restrict__ t3) {
  const int z = blockIdx.z;
  const float* w = z == 0 ? w0 : (z == 1 ? w1 : (z == 2 ? w2 : w3));
  u16* t = z == 0 ? t0 : (z == 1 ? t1 : (z == 2 ? t2 : t3));
  __shared__ float tl[32][33];
  const int tid = threadIdx.x;
  const int r = tid >> 3, c4 = (tid & 7) * 4;
  const int kb = blockIdx.x * 32, nb = blockIdx.y * 32;
  float4 f = *(const float4*)&w[(size_t)(kb + r) * D_MODEL + nb + c4];
  tl[c4 + 0][r] = f.x; tl[c4 + 1][r] = f.y; tl[c4 + 2][r] = f.z; tl[c4 + 3][r] = f.w;
  __syncthreads();
  ushort4 o;
  o.x = f2bf(tl[r][c4 + 0]); o.y = f2bf(tl[r][c4 + 1]);
  o.z = f2bf(tl[r][c4 + 2]); o.w = f2bf(tl[r][c4 + 3]);
  *(ushort4*)&t[(size_t)(nb + r) * D_MODEL + kb + c4] = o;
}

// ---------------- 128x128 bf16 GEMM core (K=1024, BK=64, 4 waves, 64x64/wave) ----------------
// LDS rows padded to 72 halves (144 B) -> bank-balanced ds_read_b128 frag loads.

__device__ __forceinline__ void gemm_core(const u16* __restrict__ A, const u16* __restrict__ Bt, int m0, int n0,
                                          u16* lA, u16* lB, f32x4 (&acc)[4][4]) {
  const int tid = threadIdx.x;
  const int w = tid >> 6, l = tid & 63, ln = l & 15, quad = l >> 4;
  const int wm = (w & 1) * 64, wn = (w >> 1) * 64;
  const f32x4 z4 = {0.f, 0.f, 0.f, 0.f};
#pragma unroll
  for (int mt = 0; mt < 4; ++mt)
#pragma unroll
    for (int nt = 0; nt < 4; ++nt) acc[mt][nt] = z4;

  for (int kt = 0; kt < 16; ++kt) {
    const int k0 = kt * 64;
#pragma unroll
    for (int i = 0; i < 4; ++i) {
      const int c = i * 256 + tid;
      const int row = c >> 3, ko = (c & 7) * 8;
      *(uint4*)&lA[row * 72 + ko] = *(const uint4*)&A[(size_t)(m0 + row) * D_MODEL + k0 + ko];
      *(uint4*)&lB[row * 72 + ko] = *(const uint4*)&Bt[(size_t)(n0 + row) * D_MODEL + k0 + ko];
    }
    __syncthreads();
#pragma unroll
    for (int kk = 0; kk < 2; ++kk) {
      s16x8 a[4], b[4];
#pragma unroll
      for (int mt = 0; mt < 4; ++mt) a[mt] = lds8(&lA[(wm + mt * 16 + ln) * 72 + kk * 32 + quad * 8]);
#pragma unroll
      for (int nt = 0; nt < 4; ++nt) b[nt] = lds8(&lB[(wn + nt * 16 + ln) * 72 + kk * 32 + quad * 8]);
#pragma unroll
      for (int mt = 0; mt < 4; ++mt)
#pragma unroll
        for (int nt = 0; nt < 4; ++nt) acc[mt][nt] = mfma16(a[mt], b[nt], acc[mt][nt]);
    }
    __syncthreads();
  }
}

// QKV projections: z selects matrix. Q,K -> [bh][S][64]; V -> [bh][64][S] (transposed for PV B-frags).
__global__ __launch_bounds__(256) void gemm_qkv(const u16* __restrict__ xq, const u16* __restrict__ xk,
                                                const u16* __restrict__ xv, const u16* __restrict__ wtq,
                                                const u16* __restrict__ wtk, const u16* __restrict__ wtv,
                                                const float* __restrict__ bq, const float* __restrict__ bk,
                                                const float* __restrict__ bv, u16* __restrict__ qh,
                                                u16* __restrict__ kh, u16* __restrict__ vt) {
  __shared__ u16 lA[128 * 72];
  __shared__ u16 lB[128 * 72];
  const int z = blockIdx.z;
  const u16* A = z == 0 ? xq : (z == 1 ? xk : xv);
  const u16* Bt = z == 0 ? wtq : (z == 1 ? wtk : wtv);
  const float* bias = z == 0 ? bq : (z == 1 ? bk : bv);
  const int n0 = blockIdx.x * 128, m0 = blockIdx.y * 128;
  f32x4 acc[4][4];
  gemm_core(A, Bt, m0, n0, lA, lB, acc);

  const int tid = threadIdx.x;
  const int w = tid >> 6, l = tid & 63, ln = l & 15, quad = l >> 4;
  const int wm = (w & 1) * 64, wn = (w >> 1) * 64;
  u16* qk = z == 0 ? qh : kh;
#pragma unroll
  for (int nt = 0; nt < 4; ++nt) {
    const int n = n0 + wn + nt * 16 + ln;
    const float bb = bias[n];
    const int h = n >> 6, d = n & 63;
#pragma unroll
    for (int mt = 0; mt < 4; ++mt) {
#pragma unroll
      for (int r = 0; r < 4; ++r) {
        const int m = m0 + wm + mt * 16 + quad * 4 + r;
        const int b_ = m >> 11, s = m & 2047;
        const u16 val = f2bf(acc[mt][nt][r] + bb);
        if (z < 2)
          qk[((size_t)((b_ * NH + h) * SEQ + s)) * DH + d] = val;
        else
          vt[((size_t)((b_ * NH + h) * DH + d)) * SEQ + s] = val;
      }
    }
  }
}

// Output projection: ctx bf16 [4096][1024] @ Wo^T + bo -> fp32 d_out[0..4M)
__global__ __launch_bounds__(256) void gemm_o(const u16* __restrict__ ctx, const u16* __restrict__ wto,
                                              const float* __restrict__ bo, float* __restrict__ out0) {
  __shared__ u16 lA[128 * 72];
  __shared__ u16 lB[128 * 72];
  const int n0 = blockIdx.x * 128, m0 = blockIdx.y * 128;
  f32x4 acc[4][4];
  gemm_core(ctx, wto, m0, n0, lA, lB, acc);

  const int tid = threadIdx.x;
  const int w = tid >> 6, l = tid & 63, ln = l & 15, quad = l >> 4;
  const int wm = (w & 1) * 64, wn = (w >> 1) * 64;
#pragma unroll
  for (int nt = 0; nt < 4; ++nt) {
    const int n = n0 + wn + nt * 16 + ln;
    const float bb = bo[n];
#pragma unroll
    for (int mt = 0; mt < 4; ++mt) {
#pragma unroll
      for (int r = 0; r < 4; ++r) {
        const int m = m0 + wm + mt * 16 + quad * 4 + r;
        __builtin_nontemporal_store(acc[mt][nt][r] + bb, &out0[(size_t)m * D_MODEL + n]);
      }
    }
  }
}

// ---------------- fused attention ----------------
// grid (32 q-tiles of 64 rows, 32 bh); block 256 = 4 waves; wave w owns q rows [q0+16w, q0+16w+16)
// pass 1: online softmax stats over 16 K-tiles of 128. pass 2: recompute S, write P (fp32, NT),
// LDS round-trip P -> A-frag layout, PV MFMA accumulate; ctx out bf16 [4096][1024].
__global__ __launch_bounds__(256) void attn(const u16* __restrict__ qh, const u16* __restrict__ kh,
                                            const u16* __restrict__ vt, float* __restrict__ probs,
                                            u16* __restrict__ ctx) {
  constexpr float SCL = 0.18033688011112042f; // (1/sqrt(64)) * log2(e)
  const int bh = blockIdx.y;
  const int q0 = blockIdx.x * 64;
  const int tid = threadIdx.x;
  const int w = tid >> 6, l = tid & 63, ln = l & 15, quad = l >> 4;
  const int qrow = q0 + w * 16;

  __shared__ u16 Kt[128 * 72];     // K tile 128x64, padded stride
  __shared__ u16 Vt[64 * 136];     // V^T tile 64x128, padded stride
  __shared__ u16 Pl[4][16 * 136];  // per-wave P tile (C-layout -> A-layout transform)

  s16x8 aq[2];
  {
    const u16* qp = qh + ((size_t)(bh * SEQ + qrow + ln)) * DH + quad * 8;
    aq[0] = *(const s16x8*)qp;
    aq[1] = *(const s16x8*)(qp + 32);
  }
  const f32x4 z4 = {0.f, 0.f, 0.f, 0.f};
  float m_r[4], l_r[4];
#pragma unroll
  for (int r = 0; r < 4; ++r) { m_r[r] = -__builtin_inff(); l_r[r] = 0.f; }

  // ---- pass 1 ----
  for (int kt = 0; kt < 16; ++kt) {
#pragma unroll
    for (int i = 0; i < 4; ++i) {
      const int c = i * 256 + tid;
      const int row = c >> 3, ko = (c & 7) * 8;
      *(uint4*)&Kt[row * 72 + ko] = *(const uint4*)&kh[((size_t)(bh * SEQ + kt * 128 + row)) * DH + ko];
    }
    __syncthreads();
    f32x4 s[8];
#pragma unroll
    for (int nt = 0; nt < 8; ++nt) s[nt] = z4;
#pragma unroll
    for (int nt = 0; nt < 8; ++nt) {
      s16x8 b0 = lds8(&Kt[(nt * 16 + ln) * 72 + quad * 8]);
      s16x8 b1 = lds8(&Kt[(nt * 16 + ln) * 72 + 32 + quad * 8]);
      s[nt] = mfma16(aq[0], b0, s[nt]);
      s[nt] = mfma16(aq[1], b1, s[nt]);
    }
    __syncthreads();
#pragma unroll
    for (int r = 0; r < 4; ++r) {
      float mx = s[0][r];
#pragma unroll
      for (int nt = 1; nt < 8; ++nt) mx = fmaxf(mx, s[nt][r]);
      mx *= SCL;
      mx = qmax16(mx);
      const float mnew = fmaxf(m_r[r], mx);
      const float corr = exp2f(m_r[r] - mnew);
      float ps = 0.f;
#pragma unroll
      for (int nt = 0; nt < 8; ++nt) ps += exp2f(s[nt][r] * SCL - mnew);
      ps = qsum16(ps);
      l_r[r] = l_r[r] * corr + ps;
      m_r[r] = mnew;
    }
  }

  float rinv[4];
#pragma unroll
  for (int r = 0; r < 4; ++r) rinv[r] = 1.f / l_r[r];

  f32x4 cacc[4];
#pragma unroll
  for (int dt = 0; dt < 4; ++dt) cacc[dt] = z4;

  float* pbase = probs + ((size_t)bh * SEQ + qrow + quad * 4) * SEQ;

  // ---- pass 2 ----
  for (int kt = 0; kt < 16; ++kt) {
#pragma unroll
    for (int i = 0; i < 4; ++i) {
      const int c = i * 256 + tid;
      const int row = c >> 3, ko = (c & 7) * 8;
      *(uint4*)&Kt[row * 72 + ko] = *(const uint4*)&kh[((size_t)(bh * SEQ + kt * 128 + row)) * DH + ko];
    }
#pragma unroll
    for (int i = 0; i < 4; ++i) {
      const int c = i * 256 + tid;
      const int row = c >> 4, so = (c & 15) * 8;
      *(uint4*)&Vt[row * 136 + so] = *(const uint4*)&vt[((size_t)(bh * DH + row)) * SEQ + kt * 128 + so];
    }
    __syncthreads();
    f32x4 s[8];
#pragma unroll
    for (int nt = 0; nt < 8; ++nt) s[nt] = z4;
#pragma unroll
    for (int nt = 0; nt < 8; ++nt) {
      s16x8 b0 = lds8(&Kt[(nt * 16 + ln) * 72 + quad * 8]);
      s16x8 b1 = lds8(&Kt[(nt * 16 + ln) * 72 + 32 + quad * 8]);
      s[nt] = mfma16(aq[0], b0, s[nt]);
      s[nt] = mfma16(aq[1], b1, s[nt]);
    }
#pragma unroll
    for (int nt = 0; nt < 8; ++nt) {
#pragma unroll
      for (int r = 0; r < 4; ++r) {
        const float p = exp2f(s[nt][r] * SCL - m_r[r]) * rinv[r];
        __builtin_nontemporal_store(p, &pbase[(size_t)r * SEQ + kt * 128 + nt * 16 + ln]);
        Pl[w][(quad * 4 + r) * 136 + nt * 16 + ln] = f2bf(p);
      }
    }
#pragma unroll
    for (int kk = 0; kk < 4; ++kk) {
      s16x8 ap = lds8(&Pl[w][ln * 136 + kk * 32 + quad * 8]);
#pragma unroll
      for (int dt = 0; dt < 4; ++dt) {
        s16x8 bv = lds8(&Vt[(dt * 16 + ln) * 136 + kk * 32 + quad * 8]);
        cacc[dt] = mfma16(ap, bv, cacc[dt]);
      }
    }
    __syncthreads();
  }

  const int b_ = bh >> 4, h = bh & 15;
#pragma unroll
  for (int dt = 0; dt < 4; ++dt) {
#pragma unroll
    for (int r = 0; r < 4; ++r) {
      const int qr = qrow + quad * 4 + r;
      ctx[((size_t)(b_ * SEQ + qr)) * D_MODEL + h * DH + dt * 16 + ln] = f2bf(cacc[dt][r]);
    }
  }
}

// ---------------- launch ----------------

extern "C" void kernel_launch(void* const* d_in, const int* in_sizes, int n_in, void* d_out, int out_size,
                              void* d_ws, size_t ws_size, hipStream_t stream) {
  const float* query = (const float*)d_in[0];
  const float* key_ = (const float*)d_in[1];
  const float* value = (const float*)d_in[2];
  const float* Wq = (const float*)d_in[3];
  const float* bq = (const float*)d_in[4];
  const float* Wk = (const float*)d_in[5];
  const float* bk = (const float*)d_in[6];
  const float* Wv = (const float*)d_in[7];
  const float* bv = (const float*)d_in[8];
  const float* Wo = (const float*)d_in[9];
  const float* bo = (const float*)d_in[10];

  float* out0 = (float*)d_out;
  float* probs = out0 + (size_t)MROWS * D_MODEL;

  // workspace layout (halves). total = 29,360,128 halves = 56 MiB
  u16* ws = (u16*)d_ws;
  u16* xq = ws;                      // 4096*1024
  u16* xk = xq + (size_t)4194304;
  u16* xv = xk + (size_t)4194304;
  u16* wtq = xv + (size_t)4194304;   // 1024*1024 each
  u16* wtk = wtq + (size_t)1048576;
  u16* wtv = wtk + (size_t)1048576;
  u16* wto = wtv + (size_t)1048576;
  u16* qhb = wto + (size_t)1048576;  // [32][2048][64]
  u16* khb = qhb + (size_t)4194304;
  u16* vtb = khb + (size_t)4194304;  // [32][64][2048]
  u16* ctx = xq;                     // reuse xq region after projections

  convert_x<<<dim3(4096, 1, 3), 256, 0, stream>>>(query, key_, value, xq, xk, xv);
  transw<<<dim3(32, 32, 4), 256, 0, stream>>>(Wq, Wk, Wv, Wo, wtq, wtk, wtv, wto);
  gemm_qkv<<<dim3(8, 32, 3), 256, 0, stream>>>(xq, xk, xv, wtq, wtk, wtv, bq, bk, bv, qhb, khb, vtb);
  attn<<<dim3(32, 32), 256, 0, stream>>>(qhb, khb, vtb, probs, ctx);
  gemm_o<<<dim3(8, 32), 256, 0, stream>>>(ctx, wto, bo, out0);
}